// Round 12
// baseline (135.945 us; speedup 1.0000x reference)
//
#include <hip/hip_runtime.h>
#include <hip/hip_bf16.h>
#include <cstdint>
#include <cstddef>

// Problem constants (B,C,H,W)=(2,128,192,192), K=4, O=60
constexpr int kB = 2, kC = 128, kH = 192, kW = 192, kK = 4, kO = 60;
constexpr int kHW  = kH * kW;        // 36864
constexpr int NPIX = kB * kHW;       // 73728
constexpr int P    = 72;             // pixels per block; kHW = 512*72 -> 4 blocks/CU
constexpr int WPB  = kHW / P;        // 512 windows per image
constexpr int NWIN = NPIX / P;       // 1024 blocks = exactly 4 per CU
constexpr int MAXG = 8;              // max padded 16-groups for P=72
constexpr float kSlope = 0.01f;

// ws layout (bytes): pre-swizzled bf16 weights + f32 biases
constexpr size_t WB_OFF    = 0;        // [l*4+k][frag 32][lane 64][8] bf16 = 524288 B
constexpr size_t WB4_OFF   = 524288;   // [k][frag 16][lane 64][8] bf16   = 65536 B
constexpr size_t BIAS_OFF  = 589824;   // [l*4+k][128] f32                = 8192 B
constexpr size_t BIAS4_OFF = 598016;   // [k][64] f32 (pad 0)             = 1024 B
constexpr size_t WS_NEED   = 599040;

typedef __attribute__((ext_vector_type(8))) short bf16x8;
typedef __attribute__((ext_vector_type(4))) float f32x4;

// ---------------- dtype helpers ----------------
__device__ __forceinline__ unsigned short f2bf(float f) {
  unsigned u = __float_as_uint(f);
  u += 0x7FFF + ((u >> 16) & 1);
  return (unsigned short)(u >> 16);
}
__device__ __forceinline__ float bf2f(unsigned short u) {
  return __uint_as_float(((unsigned)u) << 16);
}
__device__ __forceinline__ float load1(const float* p) { return *p; }
__device__ __forceinline__ float load1(const __hip_bfloat16* p) {
  return bf2f(*reinterpret_cast<const unsigned short*>(p));
}
__device__ __forceinline__ bf16x8 load_wfrag(const __hip_bfloat16* p) {
  return *reinterpret_cast<const bf16x8*>(p);
}
__device__ __forceinline__ bf16x8 load_wfrag(const float* p) {
  bf16x8 r;
#pragma unroll
  for (int j = 0; j < 8; ++j) r[j] = (short)f2bf(p[j]);
  return r;
}

// LDS swizzle: row = 128 bf16 = 16 groups of 8; group g of row r lives at
// X[r][xgrp(r,g)*8]. Spreads same-group column reads across banks.
__device__ __forceinline__ int xgrp(int r, int g) {
  return (g + r + (r >> 3)) & 15;
}

// ---------------- shared block state ----------------
struct alignas(16) Smem {
  unsigned short Xs[P][kC];      // 18 KB
  unsigned short Ys[P][kC];      // 18 KB (reused as Obuf f32 [P][61])
  short ord[MAXG * 16];          // slot -> local pixel (|256 = pad)
  unsigned char kg[MAXG + 3];    // group -> class
  int cnt[kK], gpre[kK + 1], first[kK];
  int s_f32, s_onz;
};

// ---------------- prep kernel: weights -> bf16 frag layout, biases -> f32 ----
template<typename T>
__device__ __forceinline__ void prep_body(
    const T* W1, const T* Wr1, const T* Wr2, const T* W3, const T* W4,
    const T* b1, const T* br1, const T* br2, const T* b3, const T* b4,
    char* ws, int gid) {
  unsigned short* WB  = (unsigned short*)(ws + WB_OFF);
  unsigned short* WB4 = (unsigned short*)(ws + WB4_OFF);
  float* BS  = (float*)(ws + BIAS_OFF);
  float* BS4 = (float*)(ws + BIAS4_OFF);
  if (gid < 32768) {                         // main weights: 16 (l,k) * 2048 lanes
    const int lk = gid >> 11, fl = gid & 2047, f = fl >> 6, lane = fl & 63;
    const int l = lk >> 2, k = lk & 3;
    const int rb = f >> 3, oi = (f >> 2) & 1, ks = f & 3;
    const int quad = lane >> 4, col = lane & 15;
    const int row = rb * 32 + oi * 16 + col, c0 = ks * 32 + quad * 8;
    const T* Wsrc = (l == 0) ? W1 : (l == 1) ? Wr1 : (l == 2) ? Wr2 : W3;
    bf16x8 v = load_wfrag(Wsrc + ((size_t)(k * kC + row)) * kC + c0);
    *reinterpret_cast<bf16x8*>(WB + (size_t)lk * 16384 + f * 512 + lane * 8) = v;
  } else if (gid < 36864) {                  // W4: 4 k * 1024 lanes
    const int g2 = gid - 32768, k = g2 >> 10, fl = g2 & 1023, f = fl >> 6, lane = fl & 63;
    const int rb = f >> 2, ks = f & 3, quad = lane >> 4, col = lane & 15;
    const int row = rb * 16 + col, c0 = ks * 32 + quad * 8;
    bf16x8 v;
    if (row < kO) v = load_wfrag(W4 + ((size_t)(k * kO + row)) * kC + c0);
    else { for (int j = 0; j < 8; ++j) v[j] = 0; }
    *reinterpret_cast<bf16x8*>(WB4 + (size_t)k * 8192 + f * 512 + lane * 8) = v;
  } else if (gid < 38912) {                  // main biases
    const int g2 = gid - 36864, l = g2 >> 9, kn = g2 & 511, k = kn >> 7, n = kn & 127;
    const T* bsrc = (l == 0) ? b1 : (l == 1) ? br1 : (l == 2) ? br2 : b3;
    BS[g2] = load1(bsrc + k * kC + n);
  } else if (gid < 39168) {                  // b4 padded to 64
    const int g2 = gid - 38912, k = g2 >> 6, n = g2 & 63;
    BS4[g2] = (n < kO) ? load1(b4 + k * kO + n) : 0.f;
  }
}

__global__ __launch_bounds__(256) void prep_kernel(
    const void* W1, const void* Wr1, const void* Wr2, const void* W3, const void* W4,
    const void* b1, const void* br1, const void* br2, const void* b3, const void* b4,
    char* ws) {
  __shared__ int s_f32;
  if (threadIdx.x == 0) s_f32 = 0;
  __syncthreads();
  // f32 weights: even halfwords ~uniform -> exponent-field>=0x84 ~48%; bf16 never.
  const unsigned short h = ((const unsigned short*)W1)[threadIdx.x];
  if (((h >> 7) & 0xFF) >= 0x84) atomicAdd(&s_f32, 1);
  __syncthreads();
  const int gid = blockIdx.x * 256 + threadIdx.x;
  if (s_f32 > 8)
    prep_body<float>((const float*)W1, (const float*)Wr1, (const float*)Wr2,
                     (const float*)W3, (const float*)W4, (const float*)b1,
                     (const float*)br1, (const float*)br2, (const float*)b3,
                     (const float*)b4, ws, gid);
  else
    prep_body<__hip_bfloat16>((const __hip_bfloat16*)W1, (const __hip_bfloat16*)Wr1,
                              (const __hip_bfloat16*)Wr2, (const __hip_bfloat16*)W3,
                              (const __hip_bfloat16*)W4, (const __hip_bfloat16*)b1,
                              (const __hip_bfloat16*)br1, (const __hip_bfloat16*)br2,
                              (const __hip_bfloat16*)b3, (const __hip_bfloat16*)b4,
                              ws, gid);
}

// ---------------- common prologue: sniff + local class sort ----------------
template<bool SNIFFX>
__device__ __forceinline__ void prologue(const void* xraw, const void* segraw,
                                         Smem& sm, int bb, int hw0, int tid) {
  if (tid == 0) { sm.s_f32 = 0; sm.s_onz = 0; }
  if (tid < kK) sm.cnt[tid] = 0;
  __syncthreads();
  if constexpr (SNIFFX) {
    // x: bf16 halfwords never have exponent-field >= 0x84; f32 low halves ~48%.
    const unsigned short h = ((const unsigned short*)xraw)[tid];
    if (((h >> 7) & 0xFF) >= 0x84) atomicAdd(&sm.s_f32, 1);
  }
  // seg: int64 -> odd 32-bit words all zero; int32 -> ~75% nonzero.
  if (tid < 288 && (tid & 1) && ((const unsigned*)segraw)[tid] != 0)
    atomicAdd(&sm.s_onz, 1);
  __syncthreads();
  const bool is64 = (sm.s_onz < 4);
  int myk = 0, myidx = 0;
  if (tid < P) {
    const int pg = bb * kHW + hw0 + tid;
    myk = is64 ? (int)((const long long*)segraw)[pg]
               : ((const int*)segraw)[pg];
    myidx = atomicAdd(&sm.cnt[myk], 1);
    if (myidx == 0) sm.first[myk] = tid;
  }
  __syncthreads();
  if (tid == 0) {
    int g = 0;
    for (int k = 0; k < kK; ++k) {
      sm.gpre[k] = g;
      const int gc = (sm.cnt[k] + 15) >> 4;
      for (int j = 0; j < gc; ++j) sm.kg[g + j] = (unsigned char)k;
      g += gc;
    }
    sm.gpre[kK] = g;
  }
  __syncthreads();
  if (tid < P) sm.ord[sm.gpre[myk] * 16 + myidx] = (short)tid;
  const int ngrp = sm.gpre[kK];
  if (tid < ngrp * 16) {
    const int g = tid >> 4, k2 = sm.kg[g];
    const int rel = tid - sm.gpre[k2] * 16;
    if (rel >= sm.cnt[k2])                   // pad: duplicate class's first pixel
      sm.ord[tid] = (short)(sm.first[k2] | 256);
  }
  // ord/pad writes are covered by the barrier after staging.
}

// ---------------- stage window into swizzled Xs ----------------
template<typename T>
__device__ __forceinline__ void stage(const void* xraw, unsigned short (*Xs)[kC],
                                      int bb, int hw0, int tid) {
  const T* x = (const T*)xraw;
  const size_t base = (size_t)bb * kC * kHW + hw0;
  if constexpr (sizeof(T) == 4) {
    constexpr int CH = P / 4;                // 18 four-pixel chunks per channel
    constexpr int TOT = kC * CH;             // 2304
#pragma unroll
    for (int it = 0; it < (TOT + 511) / 512; ++it) {
      const int flat = it * 512 + tid;
      if (flat < TOT) {
        const int c = flat / CH, j = flat - c * CH;
        const float4 v = *reinterpret_cast<const float4*>(
            (const float*)x + base + (size_t)c * kHW + j * 4);
        const float vv[4] = {v.x, v.y, v.z, v.w};
#pragma unroll
        for (int jj = 0; jj < 4; ++jj) {
          const int r = j * 4 + jj;
          Xs[r][xgrp(r, c >> 3) * 8 + (c & 7)] = f2bf(vv[jj]);
        }
      }
    }
  } else {
    constexpr int CH = P / 8;                // 9 eight-pixel chunks per channel
    constexpr int TOT = kC * CH;             // 1152
#pragma unroll
    for (int it = 0; it < (TOT + 511) / 512; ++it) {
      const int flat = it * 512 + tid;
      if (flat < TOT) {
        const int c = flat / CH, j = flat - c * CH;
        const bf16x8 v = *reinterpret_cast<const bf16x8*>(
            (const unsigned short*)x + base + (size_t)c * kHW + j * 8);
#pragma unroll
        for (int jj = 0; jj < 8; ++jj) {
          const int r = j * 8 + jj;
          Xs[r][xgrp(r, c >> 3) * 8 + (c & 7)] = (unsigned short)v[jj];
        }
      }
    }
  }
}

// ---------------- coalesced output from Obuf[P][61] ----------------
template<typename T>
__device__ __forceinline__ void output(void* outraw, const float* Obuf,
                                       int bb, int hw0, int tid) {
  T* ob = (T*)outraw + (size_t)bb * kO * kHW + hw0;
  if constexpr (sizeof(T) == 4) {
    constexpr int QC = P / 4;                // 18
    constexpr int TOT = kO * QC;             // 1080
#pragma unroll
    for (int it = 0; it < (TOT + 511) / 512; ++it) {
      const int t = it * 512 + tid;
      if (t < TOT) {
        const int o = t / QC, q = t - o * QC;
        float4 v;
        v.x = Obuf[(q * 4 + 0) * 61 + o];
        v.y = Obuf[(q * 4 + 1) * 61 + o];
        v.z = Obuf[(q * 4 + 2) * 61 + o];
        v.w = Obuf[(q * 4 + 3) * 61 + o];
        *reinterpret_cast<float4*>((float*)ob + (size_t)o * kHW + q * 4) = v;
      }
    }
  } else {
    constexpr int QC = P / 2;                // 36
    constexpr int TOT = kO * QC;             // 2160
#pragma unroll
    for (int it = 0; it < (TOT + 511) / 512; ++it) {
      const int t = it * 512 + tid;
      if (t < TOT) {
        const int o = t / QC, q = t - o * QC;
        const unsigned u = (unsigned)f2bf(Obuf[(q * 2) * 61 + o]) |
                           ((unsigned)f2bf(Obuf[(q * 2 + 1) * 61 + o]) << 16);
        *reinterpret_cast<unsigned*>((unsigned short*)ob + (size_t)o * kHW + q * 2) = u;
      }
    }
  }
}

// ---------------- paired group body: 1 or 2 groups, 4 independent MFMA chains
template<bool LRELU, bool RES, bool PAIR>
__device__ __forceinline__ void pair_body(const unsigned short (*src)[kC],
                                          unsigned short (*dst)[kC],
                                          const bf16x8 (&a)[2][4],
                                          const float4 (&bv)[2],
                                          const Smem& sm, int g,
                                          int quad, int col, int rb) {
  constexpr int NG = PAIR ? 2 : 1;
  int ov[2], row[2];
  bf16x8 bfr[2][4];
#pragma unroll
  for (int j = 0; j < NG; ++j) {
    ov[j]  = sm.ord[(g + j) * 16 + col];
    row[j] = ov[j] & 255;
#pragma unroll
    for (int ks = 0; ks < 4; ++ks)
      bfr[j][ks] = *reinterpret_cast<const bf16x8*>(
          &src[row[j]][xgrp(row[j], ks * 4 + quad) * 8]);
  }
  f32x4 acc[2][2];
#pragma unroll
  for (int j = 0; j < NG; ++j)
#pragma unroll
    for (int oi = 0; oi < 2; ++oi) {
      acc[j][oi] = {0.f, 0.f, 0.f, 0.f};
#pragma unroll
      for (int ks = 0; ks < 4; ++ks)
        acc[j][oi] = __builtin_amdgcn_mfma_f32_16x16x32_bf16(
            a[oi][ks], bfr[j][ks], acc[j][oi], 0, 0, 0);
    }
#pragma unroll
  for (int j = 0; j < NG; ++j) {
    if (ov[j] < 256) {                       // not a pad slot
#pragma unroll
      for (int oi = 0; oi < 2; ++oi) {
        const int nb = rb * 32 + oi * 16 + quad * 4;
        unsigned short* dp = &dst[row[j]][xgrp(row[j], nb >> 3) * 8 + (nb & 7)];
        const float bb4[4] = {bv[oi].x, bv[oi].y, bv[oi].z, bv[oi].w};
        float v[4];
#pragma unroll
        for (int r = 0; r < 4; ++r) {
          float t = acc[j][oi][r] + bb4[r];
          if constexpr (LRELU) t = (t >= 0.f) ? t : kSlope * t;
          v[r] = t;
        }
        if constexpr (RES) {                 // in-place residual (lane-owned 8B)
          const short4 rv = *reinterpret_cast<const short4*>(dp);
          v[0] += bf2f((unsigned short)rv.x);
          v[1] += bf2f((unsigned short)rv.y);
          v[2] += bf2f((unsigned short)rv.z);
          v[3] += bf2f((unsigned short)rv.w);
        }
        short4 pk;
        pk.x = (short)f2bf(v[0]); pk.y = (short)f2bf(v[1]);
        pk.z = (short)f2bf(v[2]); pk.w = (short)f2bf(v[3]);
        *reinterpret_cast<short4*>(dp) = pk;
      }
    }
  }
}

// ---------------- MFMA layer (PREP weights; per-class loop, paired groups) ---
template<bool LRELU, bool RES>
__device__ __forceinline__ void layerP(const unsigned short (*src)[kC],
                                       unsigned short (*dst)[kC],
                                       const unsigned short* __restrict__ WBl,
                                       const float* __restrict__ BSl,
                                       const Smem& sm, int tid) {
  const int wave = tid >> 6, lane = tid & 63, quad = lane >> 4, col = lane & 15;
  const int rb = wave & 3, ch2 = wave >> 2;
#pragma unroll
  for (int c2 = 0; c2 < 2; ++c2) {
    const int k = ch2 * 2 + c2;              // wave-uniform
    const int gs = sm.gpre[k], ge = sm.gpre[k + 1];
    if (gs == ge) continue;
    const unsigned short* wk = WBl + (size_t)k * 16384 + lane * 8;
    bf16x8 a[2][4];
    float4 bv[2];
#pragma unroll
    for (int oi = 0; oi < 2; ++oi) {
#pragma unroll
      for (int ks = 0; ks < 4; ++ks)
        a[oi][ks] = *reinterpret_cast<const bf16x8*>(wk + (((rb * 2 + oi) * 4 + ks) << 9));
      bv[oi] = *reinterpret_cast<const float4*>(
          BSl + k * kC + rb * 32 + oi * 16 + quad * 4);
    }
    int g = gs;
    for (; g + 1 < ge; g += 2)
      pair_body<LRELU, RES, true >(src, dst, a, bv, sm, g, quad, col, rb);
    if (g < ge)
      pair_body<LRELU, RES, false>(src, dst, a, bv, sm, g, quad, col, rb);
  }
}

// ---------------- final layer (60 outs), paired --------------------------
template<bool PAIR>
__device__ __forceinline__ void pair_body5(const unsigned short (*src)[kC],
                                           float* __restrict__ Obuf,
                                           const bf16x8 (&a)[4],
                                           const float4& bv,
                                           const Smem& sm, int g,
                                           int quad, int col, int rb) {
  constexpr int NG = PAIR ? 2 : 1;
  int ov[2], row[2];
  bf16x8 bfr[2][4];
#pragma unroll
  for (int j = 0; j < NG; ++j) {
    ov[j]  = sm.ord[(g + j) * 16 + col];
    row[j] = ov[j] & 255;
#pragma unroll
    for (int ks = 0; ks < 4; ++ks)
      bfr[j][ks] = *reinterpret_cast<const bf16x8*>(
          &src[row[j]][xgrp(row[j], ks * 4 + quad) * 8]);
  }
  f32x4 acc[2];
#pragma unroll
  for (int j = 0; j < NG; ++j) {
    acc[j] = {0.f, 0.f, 0.f, 0.f};
#pragma unroll
    for (int ks = 0; ks < 4; ++ks)
      acc[j] = __builtin_amdgcn_mfma_f32_16x16x32_bf16(a[ks], bfr[j][ks], acc[j], 0, 0, 0);
  }
  const float bb4[4] = {bv.x, bv.y, bv.z, bv.w};
#pragma unroll
  for (int j = 0; j < NG; ++j) {
    if (ov[j] < 256) {
#pragma unroll
      for (int r = 0; r < 4; ++r) {
        const int n = rb * 16 + quad * 4 + r;
        if (n < kO) Obuf[row[j] * 61 + n] = acc[j][r] + bb4[r];
      }
    }
  }
}

__device__ __forceinline__ void layer5P(const unsigned short (*src)[kC],
                                        float* __restrict__ Obuf,
                                        const unsigned short* __restrict__ WB4,
                                        const float* __restrict__ BS4,
                                        const Smem& sm, int tid) {
  const int wave = tid >> 6, lane = tid & 63, quad = lane >> 4, col = lane & 15;
  const int rb = wave & 3, ch2 = wave >> 2;  // rb covers rows rb*16..+15
#pragma unroll
  for (int c2 = 0; c2 < 2; ++c2) {
    const int k = ch2 * 2 + c2;
    const int gs = sm.gpre[k], ge = sm.gpre[k + 1];
    if (gs == ge) continue;
    const unsigned short* wk = WB4 + (size_t)k * 8192 + lane * 8;
    bf16x8 a[4];
#pragma unroll
    for (int ks = 0; ks < 4; ++ks)
      a[ks] = *reinterpret_cast<const bf16x8*>(wk + ((rb * 4 + ks) << 9));
    const float4 bv = *reinterpret_cast<const float4*>(
        BS4 + k * 64 + rb * 16 + quad * 4);
    int g = gs;
    for (; g + 1 < ge; g += 2)
      pair_body5<true >(src, Obuf, a, bv, sm, g, quad, col, rb);
    if (g < ge)
      pair_body5<false>(src, Obuf, a, bv, sm, g, quad, col, rb);
  }
}

// ---------------- main fused kernel (PREP path only) ----------------
__global__ __launch_bounds__(512, 4) void fused_main(const void* xraw, const void* segraw,
                                                     void* outraw,
                                                     const char* __restrict__ ws) {
  __shared__ Smem sm;
  const int tid = threadIdx.x, wi = blockIdx.x;
  const int bb = wi / WPB, hw0 = (wi - bb * WPB) * P;
  prologue<true>(xraw, segraw, sm, bb, hw0, tid);
  const bool isf32 = (sm.s_f32 > 16);
  if (isf32) stage<float>(xraw, sm.Xs, bb, hw0, tid);
  else       stage<__hip_bfloat16>(xraw, sm.Xs, bb, hw0, tid);
  __syncthreads();

  const unsigned short* WB  = (const unsigned short*)(ws + WB_OFF);
  const unsigned short* WB4 = (const unsigned short*)(ws + WB4_OFF);
  const float* BS  = (const float*)(ws + BIAS_OFF);
  const float* BS4 = (const float*)(ws + BIAS4_OFF);

  layerP<false, false>(sm.Xs, sm.Ys, WB,              BS,        sm, tid); __syncthreads();
  layerP<true,  false>(sm.Ys, sm.Xs, WB + 4 * 16384,  BS + 512,  sm, tid); __syncthreads();
  layerP<false, true >(sm.Xs, sm.Ys, WB + 8 * 16384,  BS + 1024, sm, tid); __syncthreads();
  layerP<true,  false>(sm.Ys, sm.Xs, WB + 12 * 16384, BS + 1536, sm, tid); __syncthreads();
  float* Obuf = (float*)sm.Ys;                 // Ys dead; [P][61] f32 = 17568 B
  layer5P(sm.Xs, Obuf, WB4, BS4, sm, tid);     __syncthreads();

  if (isf32) output<float>(outraw, Obuf, bb, hw0, tid);
  else       output<__hip_bfloat16>(outraw, Obuf, bb, hw0, tid);
}

// ---------------- fallback (no workspace): direct global weights ------------
template<typename T, bool LRELU, bool RES>
__device__ __forceinline__ void layerF(const unsigned short (*src)[kC],
                                       unsigned short (*dst)[kC],
                                       const T* __restrict__ W,
                                       const T* __restrict__ bia,
                                       const Smem& sm, int tid) {
  const int wave = tid >> 6, lane = tid & 63, quad = lane >> 4, col = lane & 15;
  const int rb = wave & 3, ch2 = wave >> 2;
  const int gs = sm.gpre[ch2 * 2], ge = sm.gpre[ch2 * 2 + 2];
  int curk = -1;
  bf16x8 a[2][4];
  float bs[2][4];
  for (int g = gs; g < ge; ++g) {
    const int k = sm.kg[g];
    if (k != curk) {
      curk = k;
      const T* Wk = W + (size_t)k * kC * kC;
      const T* bk = bia + (size_t)k * kC;
#pragma unroll
      for (int oi = 0; oi < 2; ++oi) {
        const int ra = rb * 32 + oi * 16 + col;
#pragma unroll
        for (int ks = 0; ks < 4; ++ks)
          a[oi][ks] = load_wfrag(Wk + (size_t)ra * kC + ks * 32 + quad * 8);
#pragma unroll
        for (int r = 0; r < 4; ++r)
          bs[oi][r] = load1(bk + rb * 32 + oi * 16 + quad * 4 + r);
      }
    }
    const int ov  = sm.ord[g * 16 + col];
    const int row = ov & 255;
    bf16x8 bfr[4];
#pragma unroll
    for (int ks = 0; ks < 4; ++ks)
      bfr[ks] = *reinterpret_cast<const bf16x8*>(&src[row][xgrp(row, ks * 4 + quad) * 8]);
#pragma unroll
    for (int oi = 0; oi < 2; ++oi) {
      f32x4 acc = {0.f, 0.f, 0.f, 0.f};
#pragma unroll
      for (int ks = 0; ks < 4; ++ks)
        acc = __builtin_amdgcn_mfma_f32_16x16x32_bf16(a[oi][ks], bfr[ks], acc, 0, 0, 0);
      if (ov < 256) {
        const int nb = rb * 32 + oi * 16 + quad * 4;
        unsigned short* dp = &dst[row][xgrp(row, nb >> 3) * 8 + (nb & 7)];
        float v[4];
#pragma unroll
        for (int r = 0; r < 4; ++r) {
          float t = acc[r] + bs[oi][r];
          if constexpr (LRELU) t = (t >= 0.f) ? t : kSlope * t;
          v[r] = t;
        }
        if constexpr (RES) {
          const short4 rv = *reinterpret_cast<const short4*>(dp);
          v[0] += bf2f((unsigned short)rv.x);
          v[1] += bf2f((unsigned short)rv.y);
          v[2] += bf2f((unsigned short)rv.z);
          v[3] += bf2f((unsigned short)rv.w);
        }
        short4 pk;
        pk.x = (short)f2bf(v[0]); pk.y = (short)f2bf(v[1]);
        pk.z = (short)f2bf(v[2]); pk.w = (short)f2bf(v[3]);
        *reinterpret_cast<short4*>(dp) = pk;
      }
    }
  }
}

template<typename T>
__device__ __forceinline__ void layer5F(const unsigned short (*src)[kC],
                                        float* __restrict__ Obuf,
                                        const T* __restrict__ W4,
                                        const T* __restrict__ b4,
                                        const Smem& sm, int tid) {
  const int wave = tid >> 6, lane = tid & 63, quad = lane >> 4, col = lane & 15;
  const int rb = wave & 3, ch2 = wave >> 2;
  const int gs = sm.gpre[ch2 * 2], ge = sm.gpre[ch2 * 2 + 2];
  int curk = -1;
  bf16x8 a[4];
  float bs[4];
  for (int g = gs; g < ge; ++g) {
    const int k = sm.kg[g];
    if (k != curk) {
      curk = k;
      const T* Wk = W4 + (size_t)k * kO * kC;
      const T* bk = b4 + (size_t)k * kO;
      const int ra = min(rb * 16 + col, kO - 1);
#pragma unroll
      for (int ks = 0; ks < 4; ++ks)
        a[ks] = load_wfrag(Wk + (size_t)ra * kC + ks * 32 + quad * 8);
#pragma unroll
      for (int r = 0; r < 4; ++r) {
        const int n = rb * 16 + quad * 4 + r;
        bs[r] = (n < kO) ? load1(bk + n) : 0.f;
      }
    }
    const int ov  = sm.ord[g * 16 + col];
    const int row = ov & 255;
    bf16x8 bfr[4];
#pragma unroll
    for (int ks = 0; ks < 4; ++ks)
      bfr[ks] = *reinterpret_cast<const bf16x8*>(&src[row][xgrp(row, ks * 4 + quad) * 8]);
    f32x4 acc = {0.f, 0.f, 0.f, 0.f};
#pragma unroll
    for (int ks = 0; ks < 4; ++ks)
      acc = __builtin_amdgcn_mfma_f32_16x16x32_bf16(a[ks], bfr[ks], acc, 0, 0, 0);
    if (ov < 256) {
#pragma unroll
      for (int r = 0; r < 4; ++r) {
        const int n = rb * 16 + quad * 4 + r;
        if (n < kO) Obuf[row * 61 + n] = acc[r] + bs[r];
      }
    }
  }
}

template<typename T>
__device__ __forceinline__ void run_fall(
    const void* xraw, void* outraw,
    const void* W1, const void* b1, const void* Wr1, const void* br1,
    const void* Wr2, const void* br2, const void* W3, const void* b3,
    const void* W4, const void* b4,
    Smem& sm, int bb, int hw0, int tid) {
  stage<T>(xraw, sm.Xs, bb, hw0, tid);
  __syncthreads();
  layerF<T, false, false>(sm.Xs, sm.Ys, (const T*)W1,  (const T*)b1,  sm, tid); __syncthreads();
  layerF<T, true,  false>(sm.Ys, sm.Xs, (const T*)Wr1, (const T*)br1, sm, tid); __syncthreads();
  layerF<T, false, true >(sm.Xs, sm.Ys, (const T*)Wr2, (const T*)br2, sm, tid); __syncthreads();
  layerF<T, true,  false>(sm.Ys, sm.Xs, (const T*)W3,  (const T*)b3,  sm, tid); __syncthreads();
  float* Obuf = (float*)sm.Ys;
  layer5F<T>(sm.Xs, Obuf, (const T*)W4, (const T*)b4, sm, tid);
  __syncthreads();
  output<T>(outraw, Obuf, bb, hw0, tid);
}

__global__ __launch_bounds__(512) void fused_fallback(
    const void* xraw, const void* segraw,
    const void* W1, const void* b1, const void* Wr1, const void* br1,
    const void* Wr2, const void* br2, const void* W3, const void* b3,
    const void* W4, const void* b4, void* outraw) {
  __shared__ Smem sm;
  const int tid = threadIdx.x, wi = blockIdx.x;
  const int bb = wi / WPB, hw0 = (wi - bb * WPB) * P;
  prologue<true>(xraw, segraw, sm, bb, hw0, tid);
  if (sm.s_f32 > 16)
    run_fall<float>(xraw, outraw, W1, b1, Wr1, br1, Wr2, br2, W3, b3, W4, b4,
                    sm, bb, hw0, tid);
  else
    run_fall<__hip_bfloat16>(xraw, outraw, W1, b1, Wr1, br1, Wr2, br2, W3, b3, W4, b4,
                             sm, bb, hw0, tid);
}

extern "C" void kernel_launch(void* const* d_in, const int* in_sizes, int n_in,
                              void* d_out, int out_size, void* d_ws, size_t ws_size,
                              hipStream_t stream) {
  (void)in_sizes; (void)n_in; (void)out_size;
  const int prep = (d_ws != nullptr && ws_size >= WS_NEED) ? 1 : 0;
  if (prep) {
    prep_kernel<<<153, 256, 0, stream>>>(
        d_in[2], d_in[4], d_in[6], d_in[8], d_in[10],
        d_in[3], d_in[5], d_in[7], d_in[9], d_in[11], (char*)d_ws);
    fused_main<<<NWIN, 512, 0, stream>>>(d_in[0], d_in[1], d_out, (const char*)d_ws);
  } else {
    fused_fallback<<<NWIN, 512, 0, stream>>>(
        d_in[0], d_in[1], d_in[2], d_in[3], d_in[4], d_in[5], d_in[6], d_in[7],
        d_in[8], d_in[9], d_in[10], d_in[11], d_out);
  }
}

// Round 13
// 130.379 us; speedup vs baseline: 1.0427x; 1.0427x over previous
//
#include <hip/hip_runtime.h>
#include <hip/hip_bf16.h>
#include <cstdint>
#include <cstddef>

// Problem constants (B,C,H,W)=(2,128,192,192), K=4, O=60
constexpr int kB = 2, kC = 128, kH = 192, kW = 192, kK = 4, kO = 60;
constexpr int kHW  = kH * kW;        // 36864
constexpr int NPIX = kB * kHW;       // 73728
constexpr int P    = 96;             // pixels per block; kHW = 384*96
constexpr int WPB  = kHW / P;        // 384 windows per image
constexpr int NWIN = NPIX / P;       // 768 blocks -> 3 blocks/CU (measured optimum)
constexpr int MAXG = 9;              // max padded 16-groups (3*1 + ceil(93/16))
constexpr float kSlope = 0.01f;

// ws layout (bytes): pre-swizzled bf16 weights + f32 biases
constexpr size_t WB_OFF    = 0;        // [l*4+k][frag 32][lane 64][8] bf16 = 524288 B
constexpr size_t WB4_OFF   = 524288;   // [k][frag 16][lane 64][8] bf16   = 65536 B
constexpr size_t BIAS_OFF  = 589824;   // [l*4+k][128] f32                = 8192 B
constexpr size_t BIAS4_OFF = 598016;   // [k][64] f32 (pad 0)             = 1024 B
constexpr size_t WS_NEED   = 599040;

typedef __attribute__((ext_vector_type(8))) short bf16x8;
typedef __attribute__((ext_vector_type(4))) float f32x4;

// ---------------- dtype helpers ----------------
__device__ __forceinline__ unsigned short f2bf(float f) {
  unsigned u = __float_as_uint(f);
  u += 0x7FFF + ((u >> 16) & 1);
  return (unsigned short)(u >> 16);
}
__device__ __forceinline__ float bf2f(unsigned short u) {
  return __uint_as_float(((unsigned)u) << 16);
}
__device__ __forceinline__ float load1(const float* p) { return *p; }
__device__ __forceinline__ float load1(const __hip_bfloat16* p) {
  return bf2f(*reinterpret_cast<const unsigned short*>(p));
}
__device__ __forceinline__ bf16x8 load_wfrag(const __hip_bfloat16* p) {
  return *reinterpret_cast<const bf16x8*>(p);
}
__device__ __forceinline__ bf16x8 load_wfrag(const float* p) {
  bf16x8 r;
#pragma unroll
  for (int j = 0; j < 8; ++j) r[j] = (short)f2bf(p[j]);
  return r;
}

// LDS swizzle: row = 128 bf16 = 16 groups of 8; group g of row r lives at
// X[r][xgrp(r,g)*8]. Spreads same-group column reads across banks.
__device__ __forceinline__ int xgrp(int r, int g) {
  return (g + r + (r >> 3)) & 15;
}

// ---------------- shared block state ----------------
struct alignas(16) Smem {
  unsigned short Xs[P][kC];      // 24 KB
  unsigned short Ys[P][kC];      // 24 KB (reused as Obuf f32 [P][61])
  short ord[MAXG * 16];          // slot -> local pixel (|256 = pad)
  unsigned char kg[MAXG + 3];    // group -> class
  int cnt[kK], gpre[kK + 1], first[kK];
  int s_f32, s_onz;
};

// ---------------- prep kernel: weights -> bf16 frag layout, biases -> f32 ----
template<typename T>
__device__ __forceinline__ void prep_body(
    const T* W1, const T* Wr1, const T* Wr2, const T* W3, const T* W4,
    const T* b1, const T* br1, const T* br2, const T* b3, const T* b4,
    char* ws, int gid) {
  unsigned short* WB  = (unsigned short*)(ws + WB_OFF);
  unsigned short* WB4 = (unsigned short*)(ws + WB4_OFF);
  float* BS  = (float*)(ws + BIAS_OFF);
  float* BS4 = (float*)(ws + BIAS4_OFF);
  if (gid < 32768) {                         // main weights: 16 (l,k) * 2048 lanes
    const int lk = gid >> 11, fl = gid & 2047, f = fl >> 6, lane = fl & 63;
    const int l = lk >> 2, k = lk & 3;
    const int rb = f >> 3, oi = (f >> 2) & 1, ks = f & 3;
    const int quad = lane >> 4, col = lane & 15;
    const int row = rb * 32 + oi * 16 + col, c0 = ks * 32 + quad * 8;
    const T* Wsrc = (l == 0) ? W1 : (l == 1) ? Wr1 : (l == 2) ? Wr2 : W3;
    bf16x8 v = load_wfrag(Wsrc + ((size_t)(k * kC + row)) * kC + c0);
    *reinterpret_cast<bf16x8*>(WB + (size_t)lk * 16384 + f * 512 + lane * 8) = v;
  } else if (gid < 36864) {                  // W4: 4 k * 1024 lanes
    const int g2 = gid - 32768, k = g2 >> 10, fl = g2 & 1023, f = fl >> 6, lane = fl & 63;
    const int rb = f >> 2, ks = f & 3, quad = lane >> 4, col = lane & 15;
    const int row = rb * 16 + col, c0 = ks * 32 + quad * 8;
    bf16x8 v;
    if (row < kO) v = load_wfrag(W4 + ((size_t)(k * kO + row)) * kC + c0);
    else { for (int j = 0; j < 8; ++j) v[j] = 0; }
    *reinterpret_cast<bf16x8*>(WB4 + (size_t)k * 8192 + f * 512 + lane * 8) = v;
  } else if (gid < 38912) {                  // main biases
    const int g2 = gid - 36864, l = g2 >> 9, kn = g2 & 511, k = kn >> 7, n = kn & 127;
    const T* bsrc = (l == 0) ? b1 : (l == 1) ? br1 : (l == 2) ? br2 : b3;
    BS[g2] = load1(bsrc + k * kC + n);
  } else if (gid < 39168) {                  // b4 padded to 64
    const int g2 = gid - 38912, k = g2 >> 6, n = g2 & 63;
    BS4[g2] = (n < kO) ? load1(b4 + k * kO + n) : 0.f;
  }
}

__global__ __launch_bounds__(256) void prep_kernel(
    const void* W1, const void* Wr1, const void* Wr2, const void* W3, const void* W4,
    const void* b1, const void* br1, const void* br2, const void* b3, const void* b4,
    char* ws) {
  __shared__ int s_f32;
  if (threadIdx.x == 0) s_f32 = 0;
  __syncthreads();
  // f32 weights: even halfwords ~uniform -> exponent-field>=0x84 ~48%; bf16 never.
  const unsigned short h = ((const unsigned short*)W1)[threadIdx.x];
  if (((h >> 7) & 0xFF) >= 0x84) atomicAdd(&s_f32, 1);
  __syncthreads();
  const int gid = blockIdx.x * 256 + threadIdx.x;
  if (s_f32 > 8)
    prep_body<float>((const float*)W1, (const float*)Wr1, (const float*)Wr2,
                     (const float*)W3, (const float*)W4, (const float*)b1,
                     (const float*)br1, (const float*)br2, (const float*)b3,
                     (const float*)b4, ws, gid);
  else
    prep_body<__hip_bfloat16>((const __hip_bfloat16*)W1, (const __hip_bfloat16*)Wr1,
                              (const __hip_bfloat16*)Wr2, (const __hip_bfloat16*)W3,
                              (const __hip_bfloat16*)W4, (const __hip_bfloat16*)b1,
                              (const __hip_bfloat16*)br1, (const __hip_bfloat16*)br2,
                              (const __hip_bfloat16*)b3, (const __hip_bfloat16*)b4,
                              ws, gid);
}

// ---------------- common prologue: sniff + local class sort ----------------
template<bool SNIFFX>
__device__ __forceinline__ void prologue(const void* xraw, const void* segraw,
                                         Smem& sm, int bb, int hw0, int tid) {
  if (tid == 0) { sm.s_f32 = 0; sm.s_onz = 0; }
  if (tid < kK) sm.cnt[tid] = 0;
  __syncthreads();
  if constexpr (SNIFFX) {
    // x: bf16 halfwords never have exponent-field >= 0x84; f32 low halves ~48%.
    const unsigned short h = ((const unsigned short*)xraw)[tid];
    if (((h >> 7) & 0xFF) >= 0x84) atomicAdd(&sm.s_f32, 1);
  }
  // seg: int64 -> odd 32-bit words all zero; int32 -> ~75% nonzero.
  if (tid < 288 && (tid & 1) && ((const unsigned*)segraw)[tid] != 0)
    atomicAdd(&sm.s_onz, 1);
  __syncthreads();
  const bool is64 = (sm.s_onz < 4);
  int myk = 0, myidx = 0;
  if (tid < P) {
    const int pg = bb * kHW + hw0 + tid;
    myk = is64 ? (int)((const long long*)segraw)[pg]
               : ((const int*)segraw)[pg];
    myidx = atomicAdd(&sm.cnt[myk], 1);
    if (myidx == 0) sm.first[myk] = tid;
  }
  __syncthreads();
  if (tid == 0) {
    int g = 0;
    for (int k = 0; k < kK; ++k) {
      sm.gpre[k] = g;
      const int gc = (sm.cnt[k] + 15) >> 4;
      for (int j = 0; j < gc; ++j) sm.kg[g + j] = (unsigned char)k;
      g += gc;
    }
    sm.gpre[kK] = g;
  }
  __syncthreads();
  if (tid < P) sm.ord[sm.gpre[myk] * 16 + myidx] = (short)tid;
  const int ngrp = sm.gpre[kK];
  if (tid < ngrp * 16) {
    const int g = tid >> 4, k2 = sm.kg[g];
    const int rel = tid - sm.gpre[k2] * 16;
    if (rel >= sm.cnt[k2])                   // pad: duplicate class's first pixel
      sm.ord[tid] = (short)(sm.first[k2] | 256);
  }
  // ord/pad writes are covered by the barrier after staging.
}

// ---------------- stage window into swizzled Xs ----------------
template<typename T>
__device__ __forceinline__ void stage(const void* xraw, unsigned short (*Xs)[kC],
                                      int bb, int hw0, int tid) {
  const T* x = (const T*)xraw;
  const size_t base = (size_t)bb * kC * kHW + hw0;
  if constexpr (sizeof(T) == 4) {
#pragma unroll
    for (int it = 0; it < 6; ++it) {         // 128 ch * 24 four-pixel chunks
      const int flat = it * 512 + tid;       // < 3072
      const int c = flat / 24, j = flat - c * 24;
      const float4 v = *reinterpret_cast<const float4*>(
          (const float*)x + base + (size_t)c * kHW + j * 4);
      const float vv[4] = {v.x, v.y, v.z, v.w};
#pragma unroll
      for (int jj = 0; jj < 4; ++jj) {
        const int r = j * 4 + jj;
        Xs[r][xgrp(r, c >> 3) * 8 + (c & 7)] = f2bf(vv[jj]);
      }
    }
  } else {
#pragma unroll
    for (int it = 0; it < 3; ++it) {         // 128 ch * 12 eight-pixel chunks
      const int flat = it * 512 + tid;       // < 1536
      const int c = flat / 12, j = flat - c * 12;
      const bf16x8 v = *reinterpret_cast<const bf16x8*>(
          (const unsigned short*)x + base + (size_t)c * kHW + j * 8);
#pragma unroll
      for (int jj = 0; jj < 8; ++jj) {
        const int r = j * 8 + jj;
        Xs[r][xgrp(r, c >> 3) * 8 + (c & 7)] = (unsigned short)v[jj];
      }
    }
  }
}

// ---------------- coalesced output from Obuf[P][61] ----------------
template<typename T>
__device__ __forceinline__ void output(void* outraw, const float* Obuf,
                                       int bb, int hw0, int tid) {
  T* ob = (T*)outraw + (size_t)bb * kO * kHW + hw0;
  if constexpr (sizeof(T) == 4) {
#pragma unroll
    for (int it = 0; it < 3; ++it) {
      const int t = it * 512 + tid;          // < 1440 = 60*24
      if (t < 1440) {
        const int o = t / 24, q = t - o * 24;
        float4 v;
        v.x = Obuf[(q * 4 + 0) * 61 + o];
        v.y = Obuf[(q * 4 + 1) * 61 + o];
        v.z = Obuf[(q * 4 + 2) * 61 + o];
        v.w = Obuf[(q * 4 + 3) * 61 + o];
        *reinterpret_cast<float4*>((float*)ob + (size_t)o * kHW + q * 4) = v;
      }
    }
  } else {
#pragma unroll
    for (int it = 0; it < 6; ++it) {
      const int t = it * 512 + tid;          // < 2880 = 60*48
      if (t < 2880) {
        const int o = t / 48, q = t - o * 48;
        const unsigned u = (unsigned)f2bf(Obuf[(q * 2) * 61 + o]) |
                           ((unsigned)f2bf(Obuf[(q * 2 + 1) * 61 + o]) << 16);
        *reinterpret_cast<unsigned*>((unsigned short*)ob + (size_t)o * kHW + q * 2) = u;
      }
    }
  }
}

// ---------------- paired group body: 1 or 2 groups, 4 independent MFMA chains
template<bool LRELU, bool RES, bool PAIR>
__device__ __forceinline__ void pair_body(const unsigned short (*src)[kC],
                                          unsigned short (*dst)[kC],
                                          const bf16x8 (&a)[2][4],
                                          const float4 (&bv)[2],
                                          const Smem& sm, int g,
                                          int quad, int col, int rb) {
  constexpr int NG = PAIR ? 2 : 1;
  int ov[2], row[2];
  bf16x8 bfr[2][4];
#pragma unroll
  for (int j = 0; j < NG; ++j) {
    ov[j]  = sm.ord[(g + j) * 16 + col];
    row[j] = ov[j] & 255;
#pragma unroll
    for (int ks = 0; ks < 4; ++ks)
      bfr[j][ks] = *reinterpret_cast<const bf16x8*>(
          &src[row[j]][xgrp(row[j], ks * 4 + quad) * 8]);
  }
  f32x4 acc[2][2];
#pragma unroll
  for (int j = 0; j < NG; ++j)
#pragma unroll
    for (int oi = 0; oi < 2; ++oi) {
      acc[j][oi] = {0.f, 0.f, 0.f, 0.f};
#pragma unroll
      for (int ks = 0; ks < 4; ++ks)
        acc[j][oi] = __builtin_amdgcn_mfma_f32_16x16x32_bf16(
            a[oi][ks], bfr[j][ks], acc[j][oi], 0, 0, 0);
    }
#pragma unroll
  for (int j = 0; j < NG; ++j) {
    if (ov[j] < 256) {                       // not a pad slot
#pragma unroll
      for (int oi = 0; oi < 2; ++oi) {
        const int nb = rb * 32 + oi * 16 + quad * 4;
        unsigned short* dp = &dst[row[j]][xgrp(row[j], nb >> 3) * 8 + (nb & 7)];
        const float bb4[4] = {bv[oi].x, bv[oi].y, bv[oi].z, bv[oi].w};
        float v[4];
#pragma unroll
        for (int r = 0; r < 4; ++r) {
          float t = acc[j][oi][r] + bb4[r];
          if constexpr (LRELU) t = (t >= 0.f) ? t : kSlope * t;
          v[r] = t;
        }
        if constexpr (RES) {                 // in-place residual (lane-owned 8B)
          const short4 rv = *reinterpret_cast<const short4*>(dp);
          v[0] += bf2f((unsigned short)rv.x);
          v[1] += bf2f((unsigned short)rv.y);
          v[2] += bf2f((unsigned short)rv.z);
          v[3] += bf2f((unsigned short)rv.w);
        }
        short4 pk;
        pk.x = (short)f2bf(v[0]); pk.y = (short)f2bf(v[1]);
        pk.z = (short)f2bf(v[2]); pk.w = (short)f2bf(v[3]);
        *reinterpret_cast<short4*>(dp) = pk;
      }
    }
  }
}

// ---------------- MFMA layer (PREP weights; per-class loop, paired groups) ---
template<bool LRELU, bool RES>
__device__ __forceinline__ void layerP(const unsigned short (*src)[kC],
                                       unsigned short (*dst)[kC],
                                       const unsigned short* __restrict__ WBl,
                                       const float* __restrict__ BSl,
                                       const Smem& sm, int tid) {
  const int wave = tid >> 6, lane = tid & 63, quad = lane >> 4, col = lane & 15;
  const int rb = wave & 3, ch2 = wave >> 2;
#pragma unroll
  for (int c2 = 0; c2 < 2; ++c2) {
    const int k = ch2 * 2 + c2;              // wave-uniform
    const int gs = sm.gpre[k], ge = sm.gpre[k + 1];
    if (gs == ge) continue;
    const unsigned short* wk = WBl + (size_t)k * 16384 + lane * 8;
    bf16x8 a[2][4];
    float4 bv[2];
#pragma unroll
    for (int oi = 0; oi < 2; ++oi) {
#pragma unroll
      for (int ks = 0; ks < 4; ++ks)
        a[oi][ks] = *reinterpret_cast<const bf16x8*>(wk + (((rb * 2 + oi) * 4 + ks) << 9));
      bv[oi] = *reinterpret_cast<const float4*>(
          BSl + k * kC + rb * 32 + oi * 16 + quad * 4);
    }
    int g = gs;
    for (; g + 1 < ge; g += 2)
      pair_body<LRELU, RES, true >(src, dst, a, bv, sm, g, quad, col, rb);
    if (g < ge)
      pair_body<LRELU, RES, false>(src, dst, a, bv, sm, g, quad, col, rb);
  }
}

// ---------------- final layer (60 outs), paired --------------------------
template<bool PAIR>
__device__ __forceinline__ void pair_body5(const unsigned short (*src)[kC],
                                           float* __restrict__ Obuf,
                                           const bf16x8 (&a)[4],
                                           const float4& bv,
                                           const Smem& sm, int g,
                                           int quad, int col, int rb) {
  constexpr int NG = PAIR ? 2 : 1;
  int ov[2], row[2];
  bf16x8 bfr[2][4];
#pragma unroll
  for (int j = 0; j < NG; ++j) {
    ov[j]  = sm.ord[(g + j) * 16 + col];
    row[j] = ov[j] & 255;
#pragma unroll
    for (int ks = 0; ks < 4; ++ks)
      bfr[j][ks] = *reinterpret_cast<const bf16x8*>(
          &src[row[j]][xgrp(row[j], ks * 4 + quad) * 8]);
  }
  f32x4 acc[2];
#pragma unroll
  for (int j = 0; j < NG; ++j) {
    acc[j] = {0.f, 0.f, 0.f, 0.f};
#pragma unroll
    for (int ks = 0; ks < 4; ++ks)
      acc[j] = __builtin_amdgcn_mfma_f32_16x16x32_bf16(a[ks], bfr[j][ks], acc[j], 0, 0, 0);
  }
  const float bb4[4] = {bv.x, bv.y, bv.z, bv.w};
#pragma unroll
  for (int j = 0; j < NG; ++j) {
    if (ov[j] < 256) {
#pragma unroll
      for (int r = 0; r < 4; ++r) {
        const int n = rb * 16 + quad * 4 + r;
        if (n < kO) Obuf[row[j] * 61 + n] = acc[j][r] + bb4[r];
      }
    }
  }
}

__device__ __forceinline__ void layer5P(const unsigned short (*src)[kC],
                                        float* __restrict__ Obuf,
                                        const unsigned short* __restrict__ WB4,
                                        const float* __restrict__ BS4,
                                        const Smem& sm, int tid) {
  const int wave = tid >> 6, lane = tid & 63, quad = lane >> 4, col = lane & 15;
  const int rb = wave & 3, ch2 = wave >> 2;  // rb covers rows rb*16..+15
#pragma unroll
  for (int c2 = 0; c2 < 2; ++c2) {
    const int k = ch2 * 2 + c2;
    const int gs = sm.gpre[k], ge = sm.gpre[k + 1];
    if (gs == ge) continue;
    const unsigned short* wk = WB4 + (size_t)k * 8192 + lane * 8;
    bf16x8 a[4];
#pragma unroll
    for (int ks = 0; ks < 4; ++ks)
      a[ks] = *reinterpret_cast<const bf16x8*>(wk + ((rb * 4 + ks) << 9));
    const float4 bv = *reinterpret_cast<const float4*>(
        BS4 + k * 64 + rb * 16 + quad * 4);
    int g = gs;
    for (; g + 1 < ge; g += 2)
      pair_body5<true >(src, Obuf, a, bv, sm, g, quad, col, rb);
    if (g < ge)
      pair_body5<false>(src, Obuf, a, bv, sm, g, quad, col, rb);
  }
}

// ---------------- main fused kernel (PREP path only) ----------------
__global__ __launch_bounds__(512, 4) void fused_main(const void* xraw, const void* segraw,
                                                     void* outraw,
                                                     const char* __restrict__ ws) {
  __shared__ Smem sm;
  const int tid = threadIdx.x, wi = blockIdx.x;
  const int bb = wi / WPB, hw0 = (wi - bb * WPB) * P;
  prologue<true>(xraw, segraw, sm, bb, hw0, tid);
  const bool isf32 = (sm.s_f32 > 16);
  if (isf32) stage<float>(xraw, sm.Xs, bb, hw0, tid);
  else       stage<__hip_bfloat16>(xraw, sm.Xs, bb, hw0, tid);
  __syncthreads();

  const unsigned short* WB  = (const unsigned short*)(ws + WB_OFF);
  const unsigned short* WB4 = (const unsigned short*)(ws + WB4_OFF);
  const float* BS  = (const float*)(ws + BIAS_OFF);
  const float* BS4 = (const float*)(ws + BIAS4_OFF);

  layerP<false, false>(sm.Xs, sm.Ys, WB,              BS,        sm, tid); __syncthreads();
  layerP<true,  false>(sm.Ys, sm.Xs, WB + 4 * 16384,  BS + 512,  sm, tid); __syncthreads();
  layerP<false, true >(sm.Xs, sm.Ys, WB + 8 * 16384,  BS + 1024, sm, tid); __syncthreads();
  layerP<true,  false>(sm.Ys, sm.Xs, WB + 12 * 16384, BS + 1536, sm, tid); __syncthreads();
  float* Obuf = (float*)sm.Ys;                 // Ys dead; [P][61] f32 = 23424 B
  layer5P(sm.Xs, Obuf, WB4, BS4, sm, tid);     __syncthreads();

  if (isf32) output<float>(outraw, Obuf, bb, hw0, tid);
  else       output<__hip_bfloat16>(outraw, Obuf, bb, hw0, tid);
}

// ---------------- fallback (no workspace): direct global weights ------------
template<typename T, bool LRELU, bool RES>
__device__ __forceinline__ void layerF(const unsigned short (*src)[kC],
                                       unsigned short (*dst)[kC],
                                       const T* __restrict__ W,
                                       const T* __restrict__ bia,
                                       const Smem& sm, int tid) {
  const int wave = tid >> 6, lane = tid & 63, quad = lane >> 4, col = lane & 15;
  const int rb = wave & 3, ch2 = wave >> 2;
  const int gs = sm.gpre[ch2 * 2], ge = sm.gpre[ch2 * 2 + 2];
  int curk = -1;
  bf16x8 a[2][4];
  float bs[2][4];
  for (int g = gs; g < ge; ++g) {
    const int k = sm.kg[g];
    if (k != curk) {
      curk = k;
      const T* Wk = W + (size_t)k * kC * kC;
      const T* bk = bia + (size_t)k * kC;
#pragma unroll
      for (int oi = 0; oi < 2; ++oi) {
        const int ra = rb * 32 + oi * 16 + col;
#pragma unroll
        for (int ks = 0; ks < 4; ++ks)
          a[oi][ks] = load_wfrag(Wk + (size_t)ra * kC + ks * 32 + quad * 8);
#pragma unroll
        for (int r = 0; r < 4; ++r)
          bs[oi][r] = load1(bk + rb * 32 + oi * 16 + quad * 4 + r);
      }
    }
    const int ov  = sm.ord[g * 16 + col];
    const int row = ov & 255;
    bf16x8 bfr[4];
#pragma unroll
    for (int ks = 0; ks < 4; ++ks)
      bfr[ks] = *reinterpret_cast<const bf16x8*>(&src[row][xgrp(row, ks * 4 + quad) * 8]);
#pragma unroll
    for (int oi = 0; oi < 2; ++oi) {
      f32x4 acc = {0.f, 0.f, 0.f, 0.f};
#pragma unroll
      for (int ks = 0; ks < 4; ++ks)
        acc = __builtin_amdgcn_mfma_f32_16x16x32_bf16(a[oi][ks], bfr[ks], acc, 0, 0, 0);
      if (ov < 256) {
        const int nb = rb * 32 + oi * 16 + quad * 4;
        unsigned short* dp = &dst[row][xgrp(row, nb >> 3) * 8 + (nb & 7)];
        float v[4];
#pragma unroll
        for (int r = 0; r < 4; ++r) {
          float t = acc[r] + bs[oi][r];
          if constexpr (LRELU) t = (t >= 0.f) ? t : kSlope * t;
          v[r] = t;
        }
        if constexpr (RES) {
          const short4 rv = *reinterpret_cast<const short4*>(dp);
          v[0] += bf2f((unsigned short)rv.x);
          v[1] += bf2f((unsigned short)rv.y);
          v[2] += bf2f((unsigned short)rv.z);
          v[3] += bf2f((unsigned short)rv.w);
        }
        short4 pk;
        pk.x = (short)f2bf(v[0]); pk.y = (short)f2bf(v[1]);
        pk.z = (short)f2bf(v[2]); pk.w = (short)f2bf(v[3]);
        *reinterpret_cast<short4*>(dp) = pk;
      }
    }
  }
}

template<typename T>
__device__ __forceinline__ void layer5F(const unsigned short (*src)[kC],
                                        float* __restrict__ Obuf,
                                        const T* __restrict__ W4,
                                        const T* __restrict__ b4,
                                        const Smem& sm, int tid) {
  const int wave = tid >> 6, lane = tid & 63, quad = lane >> 4, col = lane & 15;
  const int rb = wave & 3, ch2 = wave >> 2;
  const int gs = sm.gpre[ch2 * 2], ge = sm.gpre[ch2 * 2 + 2];
  int curk = -1;
  bf16x8 a[4];
  float bs[4];
  for (int g = gs; g < ge; ++g) {
    const int k = sm.kg[g];
    if (k != curk) {
      curk = k;
      const T* Wk = W4 + (size_t)k * kO * kC;
      const T* bk = b4 + (size_t)k * kO;
      const int ra = min(rb * 16 + col, kO - 1);
#pragma unroll
      for (int ks = 0; ks < 4; ++ks)
        a[ks] = load_wfrag(Wk + (size_t)ra * kC + ks * 32 + quad * 8);
#pragma unroll
      for (int r = 0; r < 4; ++r) {
        const int n = rb * 16 + quad * 4 + r;
        bs[r] = (n < kO) ? load1(bk + n) : 0.f;
      }
    }
    const int ov  = sm.ord[g * 16 + col];
    const int row = ov & 255;
    bf16x8 bfr[4];
#pragma unroll
    for (int ks = 0; ks < 4; ++ks)
      bfr[ks] = *reinterpret_cast<const bf16x8*>(&src[row][xgrp(row, ks * 4 + quad) * 8]);
    f32x4 acc = {0.f, 0.f, 0.f, 0.f};
#pragma unroll
    for (int ks = 0; ks < 4; ++ks)
      acc = __builtin_amdgcn_mfma_f32_16x16x32_bf16(a[ks], bfr[ks], acc, 0, 0, 0);
    if (ov < 256) {
#pragma unroll
      for (int r = 0; r < 4; ++r) {
        const int n = rb * 16 + quad * 4 + r;
        if (n < kO) Obuf[row * 61 + n] = acc[r] + bs[r];
      }
    }
  }
}

template<typename T>
__device__ __forceinline__ void run_fall(
    const void* xraw, void* outraw,
    const void* W1, const void* b1, const void* Wr1, const void* br1,
    const void* Wr2, const void* br2, const void* W3, const void* b3,
    const void* W4, const void* b4,
    Smem& sm, int bb, int hw0, int tid) {
  stage<T>(xraw, sm.Xs, bb, hw0, tid);
  __syncthreads();
  layerF<T, false, false>(sm.Xs, sm.Ys, (const T*)W1,  (const T*)b1,  sm, tid); __syncthreads();
  layerF<T, true,  false>(sm.Ys, sm.Xs, (const T*)Wr1, (const T*)br1, sm, tid); __syncthreads();
  layerF<T, false, true >(sm.Xs, sm.Ys, (const T*)Wr2, (const T*)br2, sm, tid); __syncthreads();
  layerF<T, true,  false>(sm.Ys, sm.Xs, (const T*)W3,  (const T*)b3,  sm, tid); __syncthreads();
  float* Obuf = (float*)sm.Ys;
  layer5F<T>(sm.Xs, Obuf, (const T*)W4, (const T*)b4, sm, tid);
  __syncthreads();
  output<T>(outraw, Obuf, bb, hw0, tid);
}

__global__ __launch_bounds__(512) void fused_fallback(
    const void* xraw, const void* segraw,
    const void* W1, const void* b1, const void* Wr1, const void* br1,
    const void* Wr2, const void* br2, const void* W3, const void* b3,
    const void* W4, const void* b4, void* outraw) {
  __shared__ Smem sm;
  const int tid = threadIdx.x, wi = blockIdx.x;
  const int bb = wi / WPB, hw0 = (wi - bb * WPB) * P;
  prologue<true>(xraw, segraw, sm, bb, hw0, tid);
  if (sm.s_f32 > 16)
    run_fall<float>(xraw, outraw, W1, b1, Wr1, br1, Wr2, br2, W3, b3, W4, b4,
                    sm, bb, hw0, tid);
  else
    run_fall<__hip_bfloat16>(xraw, outraw, W1, b1, Wr1, br1, Wr2, br2, W3, b3, W4, b4,
                             sm, bb, hw0, tid);
}

extern "C" void kernel_launch(void* const* d_in, const int* in_sizes, int n_in,
                              void* d_out, int out_size, void* d_ws, size_t ws_size,
                              hipStream_t stream) {
  (void)in_sizes; (void)n_in; (void)out_size;
  const int prep = (d_ws != nullptr && ws_size >= WS_NEED) ? 1 : 0;
  if (prep) {
    prep_kernel<<<153, 256, 0, stream>>>(
        d_in[2], d_in[4], d_in[6], d_in[8], d_in[10],
        d_in[3], d_in[5], d_in[7], d_in[9], d_in[11], (char*)d_ws);
    fused_main<<<NWIN, 512, 0, stream>>>(d_in[0], d_in[1], d_out, (const char*)d_ws);
  } else {
    fused_fallback<<<NWIN, 512, 0, stream>>>(
        d_in[0], d_in[1], d_in[2], d_in[3], d_in[4], d_in[5], d_in[6], d_in[7],
        d_in[8], d_in[9], d_in[10], d_in[11], d_out);
  }
}

// Round 15
// 129.098 us; speedup vs baseline: 1.0530x; 1.0099x over previous
//
#include <hip/hip_runtime.h>
#include <hip/hip_bf16.h>
#include <cstdint>
#include <cstddef>

// Problem constants (B,C,H,W)=(2,128,192,192), K=4, O=60
constexpr int kB = 2, kC = 128, kH = 192, kW = 192, kK = 4, kO = 60;
constexpr int kHW  = kH * kW;        // 36864
constexpr int NPIX = kB * kHW;       // 73728
constexpr int P    = 96;             // pixels per block; kHW = 384*96
constexpr int WPB  = kHW / P;        // 384 windows per image
constexpr int NWIN = NPIX / P;       // 768 blocks -> 3 blocks/CU (measured optimum)
constexpr int MAXG = 9;              // max padded 16-groups (3*1 + ceil(93/16))
constexpr float kSlope = 0.01f;

// ws layout (bytes): pre-swizzled bf16 weights + f32 biases
constexpr size_t WB_OFF    = 0;        // [l*4+k][frag 32][lane 64][8] bf16 = 524288 B
constexpr size_t WB4_OFF   = 524288;   // [k][frag 16][lane 64][8] bf16   = 65536 B
constexpr size_t BIAS_OFF  = 589824;   // [l*4+k][128] f32                = 8192 B
constexpr size_t BIAS4_OFF = 598016;   // [k][64] f32 (pad 0)             = 1024 B
constexpr size_t WS_NEED   = 599040;

typedef __attribute__((ext_vector_type(8))) short bf16x8;
typedef __attribute__((ext_vector_type(4))) float f32x4;

// ---------------- dtype helpers ----------------
__device__ __forceinline__ unsigned short f2bf(float f) {
  unsigned u = __float_as_uint(f);
  u += 0x7FFF + ((u >> 16) & 1);
  return (unsigned short)(u >> 16);
}
__device__ __forceinline__ float bf2f(unsigned short u) {
  return __uint_as_float(((unsigned)u) << 16);
}
__device__ __forceinline__ float load1(const float* p) { return *p; }
__device__ __forceinline__ float load1(const __hip_bfloat16* p) {
  return bf2f(*reinterpret_cast<const unsigned short*>(p));
}
__device__ __forceinline__ bf16x8 load_wfrag(const __hip_bfloat16* p) {
  return *reinterpret_cast<const bf16x8*>(p);
}
__device__ __forceinline__ bf16x8 load_wfrag(const float* p) {
  bf16x8 r;
#pragma unroll
  for (int j = 0; j < 8; ++j) r[j] = (short)f2bf(p[j]);
  return r;
}

// LDS swizzle: row = 128 bf16 = 16 groups of 8; group g of row r lives at
// X[r][xgrp(r,g)*8]. Spreads same-group column reads across banks.
__device__ __forceinline__ int xgrp(int r, int g) {
  return (g + r + (r >> 3)) & 15;
}

// ---------------- shared block state ----------------
struct alignas(16) Smem {
  unsigned short Xs[P][kC];      // 24 KB
  unsigned short Ys[P][kC];      // 24 KB (reused as Obuf f32 [P][61])
  short ord[MAXG * 16];          // slot -> local pixel (|256 = pad)
  unsigned char kg[MAXG + 3];    // group -> class
  int cnt[kK], gpre[kK + 1], first[kK];
  int s_f32, s_onz;
};

// ---------------- prep kernel: weights -> bf16 frag layout, biases -> f32 ----
template<typename T>
__device__ __forceinline__ void prep_body(
    const T* W1, const T* Wr1, const T* Wr2, const T* W3, const T* W4,
    const T* b1, const T* br1, const T* br2, const T* b3, const T* b4,
    char* ws, int gid) {
  unsigned short* WB  = (unsigned short*)(ws + WB_OFF);
  unsigned short* WB4 = (unsigned short*)(ws + WB4_OFF);
  float* BS  = (float*)(ws + BIAS_OFF);
  float* BS4 = (float*)(ws + BIAS4_OFF);
  if (gid < 32768) {                         // main weights: 16 (l,k) * 2048 lanes
    const int lk = gid >> 11, fl = gid & 2047, f = fl >> 6, lane = fl & 63;
    const int l = lk >> 2, k = lk & 3;
    const int rb = f >> 3, oi = (f >> 2) & 1, ks = f & 3;
    const int quad = lane >> 4, col = lane & 15;
    const int row = rb * 32 + oi * 16 + col, c0 = ks * 32 + quad * 8;
    const T* Wsrc = (l == 0) ? W1 : (l == 1) ? Wr1 : (l == 2) ? Wr2 : W3;
    bf16x8 v = load_wfrag(Wsrc + ((size_t)(k * kC + row)) * kC + c0);
    *reinterpret_cast<bf16x8*>(WB + (size_t)lk * 16384 + f * 512 + lane * 8) = v;
  } else if (gid < 36864) {                  // W4: 4 k * 1024 lanes
    const int g2 = gid - 32768, k = g2 >> 10, fl = g2 & 1023, f = fl >> 6, lane = fl & 63;
    const int rb = f >> 2, ks = f & 3, quad = lane >> 4, col = lane & 15;
    const int row = rb * 16 + col, c0 = ks * 32 + quad * 8;
    bf16x8 v;
    if (row < kO) v = load_wfrag(W4 + ((size_t)(k * kO + row)) * kC + c0);
    else { for (int j = 0; j < 8; ++j) v[j] = 0; }
    *reinterpret_cast<bf16x8*>(WB4 + (size_t)k * 8192 + f * 512 + lane * 8) = v;
  } else if (gid < 38912) {                  // main biases
    const int g2 = gid - 36864, l = g2 >> 9, kn = g2 & 511, k = kn >> 7, n = kn & 127;
    const T* bsrc = (l == 0) ? b1 : (l == 1) ? br1 : (l == 2) ? br2 : b3;
    BS[g2] = load1(bsrc + k * kC + n);
  } else if (gid < 39168) {                  // b4 padded to 64
    const int g2 = gid - 38912, k = g2 >> 6, n = g2 & 63;
    BS4[g2] = (n < kO) ? load1(b4 + k * kO + n) : 0.f;
  }
}

__global__ __launch_bounds__(256) void prep_kernel(
    const void* W1, const void* Wr1, const void* Wr2, const void* W3, const void* W4,
    const void* b1, const void* br1, const void* br2, const void* b3, const void* b4,
    char* ws) {
  __shared__ int s_f32;
  if (threadIdx.x == 0) s_f32 = 0;
  __syncthreads();
  // f32 weights: even halfwords ~uniform -> exponent-field>=0x84 ~48%; bf16 never.
  const unsigned short h = ((const unsigned short*)W1)[threadIdx.x];
  if (((h >> 7) & 0xFF) >= 0x84) atomicAdd(&s_f32, 1);
  __syncthreads();
  const int gid = blockIdx.x * 256 + threadIdx.x;
  if (s_f32 > 8)
    prep_body<float>((const float*)W1, (const float*)Wr1, (const float*)Wr2,
                     (const float*)W3, (const float*)W4, (const float*)b1,
                     (const float*)br1, (const float*)br2, (const float*)b3,
                     (const float*)b4, ws, gid);
  else
    prep_body<__hip_bfloat16>((const __hip_bfloat16*)W1, (const __hip_bfloat16*)Wr1,
                              (const __hip_bfloat16*)Wr2, (const __hip_bfloat16*)W3,
                              (const __hip_bfloat16*)W4, (const __hip_bfloat16*)b1,
                              (const __hip_bfloat16*)br1, (const __hip_bfloat16*)br2,
                              (const __hip_bfloat16*)b3, (const __hip_bfloat16*)b4,
                              ws, gid);
}

// ---------------- common prologue: sniff + local class sort ----------------
template<bool SNIFFX>
__device__ __forceinline__ void prologue(const void* xraw, const void* segraw,
                                         Smem& sm, int bb, int hw0, int tid) {
  if (tid == 0) { sm.s_f32 = 0; sm.s_onz = 0; }
  if (tid < kK) sm.cnt[tid] = 0;
  __syncthreads();
  if constexpr (SNIFFX) {
    // x: bf16 halfwords never have exponent-field >= 0x84; f32 low halves ~48%.
    const unsigned short h = ((const unsigned short*)xraw)[tid];
    if (((h >> 7) & 0xFF) >= 0x84) atomicAdd(&sm.s_f32, 1);
  }
  // seg: int64 -> odd 32-bit words all zero; int32 -> ~75% nonzero.
  if (tid < 288 && (tid & 1) && ((const unsigned*)segraw)[tid] != 0)
    atomicAdd(&sm.s_onz, 1);
  __syncthreads();
  const bool is64 = (sm.s_onz < 4);
  int myk = 0, myidx = 0;
  if (tid < P) {
    const int pg = bb * kHW + hw0 + tid;
    myk = is64 ? (int)((const long long*)segraw)[pg]
               : ((const int*)segraw)[pg];
    myidx = atomicAdd(&sm.cnt[myk], 1);
    if (myidx == 0) sm.first[myk] = tid;
  }
  __syncthreads();
  if (tid == 0) {
    int g = 0;
    for (int k = 0; k < kK; ++k) {
      sm.gpre[k] = g;
      const int gc = (sm.cnt[k] + 15) >> 4;
      for (int j = 0; j < gc; ++j) sm.kg[g + j] = (unsigned char)k;
      g += gc;
    }
    sm.gpre[kK] = g;
  }
  __syncthreads();
  if (tid < P) sm.ord[sm.gpre[myk] * 16 + myidx] = (short)tid;
  const int ngrp = sm.gpre[kK];
  if (tid < ngrp * 16) {
    const int g = tid >> 4, k2 = sm.kg[g];
    const int rel = tid - sm.gpre[k2] * 16;
    if (rel >= sm.cnt[k2])                   // pad: duplicate class's first pixel
      sm.ord[tid] = (short)(sm.first[k2] | 256);
  }
  // ord/pad writes are covered by the barrier after staging.
}

// ---------------- stage window into swizzled Xs ----------------
template<typename T>
__device__ __forceinline__ void stage(const void* xraw, unsigned short (*Xs)[kC],
                                      int bb, int hw0, int tid) {
  const T* x = (const T*)xraw;
  const size_t base = (size_t)bb * kC * kHW + hw0;
  if constexpr (sizeof(T) == 4) {
#pragma unroll
    for (int it = 0; it < 6; ++it) {         // 128 ch * 24 four-pixel chunks
      const int flat = it * 512 + tid;       // < 3072
      const int c = flat / 24, j = flat - c * 24;
      const float4 v = *reinterpret_cast<const float4*>(
          (const float*)x + base + (size_t)c * kHW + j * 4);
      const float vv[4] = {v.x, v.y, v.z, v.w};
#pragma unroll
      for (int jj = 0; jj < 4; ++jj) {
        const int r = j * 4 + jj;
        Xs[r][xgrp(r, c >> 3) * 8 + (c & 7)] = f2bf(vv[jj]);
      }
    }
  } else {
#pragma unroll
    for (int it = 0; it < 3; ++it) {         // 128 ch * 12 eight-pixel chunks
      const int flat = it * 512 + tid;       // < 1536
      const int c = flat / 12, j = flat - c * 12;
      const bf16x8 v = *reinterpret_cast<const bf16x8*>(
          (const unsigned short*)x + base + (size_t)c * kHW + j * 8);
#pragma unroll
      for (int jj = 0; jj < 8; ++jj) {
        const int r = j * 8 + jj;
        Xs[r][xgrp(r, c >> 3) * 8 + (c & 7)] = (unsigned short)v[jj];
      }
    }
  }
}

// ---------------- coalesced output from Obuf[P][61] ----------------
template<typename T>
__device__ __forceinline__ void output(void* outraw, const float* Obuf,
                                       int bb, int hw0, int tid) {
  T* ob = (T*)outraw + (size_t)bb * kO * kHW + hw0;
  if constexpr (sizeof(T) == 4) {
#pragma unroll
    for (int it = 0; it < 3; ++it) {
      const int t = it * 512 + tid;          // < 1440 = 60*24
      if (t < 1440) {
        const int o = t / 24, q = t - o * 24;
        float4 v;
        v.x = Obuf[(q * 4 + 0) * 61 + o];
        v.y = Obuf[(q * 4 + 1) * 61 + o];
        v.z = Obuf[(q * 4 + 2) * 61 + o];
        v.w = Obuf[(q * 4 + 3) * 61 + o];
        *reinterpret_cast<float4*>((float*)ob + (size_t)o * kHW + q * 4) = v;
      }
    }
  } else {
#pragma unroll
    for (int it = 0; it < 6; ++it) {
      const int t = it * 512 + tid;          // < 2880 = 60*48
      if (t < 2880) {
        const int o = t / 48, q = t - o * 48;
        const unsigned u = (unsigned)f2bf(Obuf[(q * 2) * 61 + o]) |
                           ((unsigned)f2bf(Obuf[(q * 2 + 1) * 61 + o]) << 16);
        *reinterpret_cast<unsigned*>((unsigned short*)ob + (size_t)o * kHW + q * 2) = u;
      }
    }
  }
}

// ---------------- paired group body: 1 or 2 groups, 4 independent MFMA chains
template<bool LRELU, bool RES, bool PAIR>
__device__ __forceinline__ void pair_body(const unsigned short (*src)[kC],
                                          unsigned short (*dst)[kC],
                                          const bf16x8 (&a)[2][4],
                                          const float4 (&bv)[2],
                                          const Smem& sm, int g,
                                          int quad, int col, int rb) {
  constexpr int NG = PAIR ? 2 : 1;
  int ov[2], row[2];
  bf16x8 bfr[2][4];
#pragma unroll
  for (int j = 0; j < NG; ++j) {
    ov[j]  = sm.ord[(g + j) * 16 + col];
    row[j] = ov[j] & 255;
#pragma unroll
    for (int ks = 0; ks < 4; ++ks)
      bfr[j][ks] = *reinterpret_cast<const bf16x8*>(
          &src[row[j]][xgrp(row[j], ks * 4 + quad) * 8]);
  }
  f32x4 acc[2][2];
#pragma unroll
  for (int j = 0; j < NG; ++j)
#pragma unroll
    for (int oi = 0; oi < 2; ++oi) {
      acc[j][oi] = {0.f, 0.f, 0.f, 0.f};
#pragma unroll
      for (int ks = 0; ks < 4; ++ks)
        acc[j][oi] = __builtin_amdgcn_mfma_f32_16x16x32_bf16(
            a[oi][ks], bfr[j][ks], acc[j][oi], 0, 0, 0);
    }
#pragma unroll
  for (int j = 0; j < NG; ++j) {
    if (ov[j] < 256) {                       // not a pad slot
#pragma unroll
      for (int oi = 0; oi < 2; ++oi) {
        const int nb = rb * 32 + oi * 16 + quad * 4;
        unsigned short* dp = &dst[row[j]][xgrp(row[j], nb >> 3) * 8 + (nb & 7)];
        const float bb4[4] = {bv[oi].x, bv[oi].y, bv[oi].z, bv[oi].w};
        float v[4];
#pragma unroll
        for (int r = 0; r < 4; ++r) {
          float t = acc[j][oi][r] + bb4[r];
          if constexpr (LRELU) t = (t >= 0.f) ? t : kSlope * t;
          v[r] = t;
        }
        if constexpr (RES) {                 // in-place residual (lane-owned 8B)
          const short4 rv = *reinterpret_cast<const short4*>(dp);
          v[0] += bf2f((unsigned short)rv.x);
          v[1] += bf2f((unsigned short)rv.y);
          v[2] += bf2f((unsigned short)rv.z);
          v[3] += bf2f((unsigned short)rv.w);
        }
        short4 pk;
        pk.x = (short)f2bf(v[0]); pk.y = (short)f2bf(v[1]);
        pk.z = (short)f2bf(v[2]); pk.w = (short)f2bf(v[3]);
        *reinterpret_cast<short4*>(dp) = pk;
      }
    }
  }
}

// ---------------- MFMA layer (PREP weights; per-class loop, paired groups) ---
template<bool LRELU, bool RES>
__device__ __forceinline__ void layerP(const unsigned short (*src)[kC],
                                       unsigned short (*dst)[kC],
                                       const unsigned short* __restrict__ WBl,
                                       const float* __restrict__ BSl,
                                       const Smem& sm, int tid) {
  const int wave = tid >> 6, lane = tid & 63, quad = lane >> 4, col = lane & 15;
  const int rb = wave & 3, ch2 = wave >> 2;
#pragma unroll
  for (int c2 = 0; c2 < 2; ++c2) {
    const int k = ch2 * 2 + c2;              // wave-uniform
    const int gs = sm.gpre[k], ge = sm.gpre[k + 1];
    if (gs == ge) continue;
    const unsigned short* wk = WBl + (size_t)k * 16384 + lane * 8;
    bf16x8 a[2][4];
    float4 bv[2];
#pragma unroll
    for (int oi = 0; oi < 2; ++oi) {
#pragma unroll
      for (int ks = 0; ks < 4; ++ks)
        a[oi][ks] = *reinterpret_cast<const bf16x8*>(wk + (((rb * 2 + oi) * 4 + ks) << 9));
      bv[oi] = *reinterpret_cast<const float4*>(
          BSl + k * kC + rb * 32 + oi * 16 + quad * 4);
    }
    int g = gs;
    for (; g + 1 < ge; g += 2)
      pair_body<LRELU, RES, true >(src, dst, a, bv, sm, g, quad, col, rb);
    if (g < ge)
      pair_body<LRELU, RES, false>(src, dst, a, bv, sm, g, quad, col, rb);
  }
}

// ---------------- final layer (60 outs), paired --------------------------
template<bool PAIR>
__device__ __forceinline__ void pair_body5(const unsigned short (*src)[kC],
                                           float* __restrict__ Obuf,
                                           const bf16x8 (&a)[4],
                                           const float4& bv,
                                           const Smem& sm, int g,
                                           int quad, int col, int rb) {
  constexpr int NG = PAIR ? 2 : 1;
  int ov[2], row[2];
  bf16x8 bfr[2][4];
#pragma unroll
  for (int j = 0; j < NG; ++j) {
    ov[j]  = sm.ord[(g + j) * 16 + col];
    row[j] = ov[j] & 255;
#pragma unroll
    for (int ks = 0; ks < 4; ++ks)
      bfr[j][ks] = *reinterpret_cast<const bf16x8*>(
          &src[row[j]][xgrp(row[j], ks * 4 + quad) * 8]);
  }
  f32x4 acc[2];
#pragma unroll
  for (int j = 0; j < NG; ++j) {
    acc[j] = {0.f, 0.f, 0.f, 0.f};
#pragma unroll
    for (int ks = 0; ks < 4; ++ks)
      acc[j] = __builtin_amdgcn_mfma_f32_16x16x32_bf16(a[ks], bfr[j][ks], acc[j], 0, 0, 0);
  }
  const float bb4[4] = {bv.x, bv.y, bv.z, bv.w};
#pragma unroll
  for (int j = 0; j < NG; ++j) {
    if (ov[j] < 256) {
#pragma unroll
      for (int r = 0; r < 4; ++r) {
        const int n = rb * 16 + quad * 4 + r;
        if (n < kO) Obuf[row[j] * 61 + n] = acc[j][r] + bb4[r];
      }
    }
  }
}

__device__ __forceinline__ void layer5P(const unsigned short (*src)[kC],
                                        float* __restrict__ Obuf,
                                        const unsigned short* __restrict__ WB4,
                                        const float* __restrict__ BS4,
                                        const Smem& sm, int tid) {
  const int wave = tid >> 6, lane = tid & 63, quad = lane >> 4, col = lane & 15;
  const int rb = wave & 3, ch2 = wave >> 2;  // rb covers rows rb*16..+15
#pragma unroll
  for (int c2 = 0; c2 < 2; ++c2) {
    const int k = ch2 * 2 + c2;
    const int gs = sm.gpre[k], ge = sm.gpre[k + 1];
    if (gs == ge) continue;
    const unsigned short* wk = WB4 + (size_t)k * 8192 + lane * 8;
    bf16x8 a[4];
#pragma unroll
    for (int ks = 0; ks < 4; ++ks)
      a[ks] = *reinterpret_cast<const bf16x8*>(wk + ((rb * 4 + ks) << 9));
    const float4 bv = *reinterpret_cast<const float4*>(
        BS4 + k * 64 + rb * 16 + quad * 4);
    int g = gs;
    for (; g + 1 < ge; g += 2)
      pair_body5<true >(src, Obuf, a, bv, sm, g, quad, col, rb);
    if (g < ge)
      pair_body5<false>(src, Obuf, a, bv, sm, g, quad, col, rb);
  }
}

// ---------------- main fused kernel (PREP path only) ----------------
__global__ __launch_bounds__(512, 4) void fused_main(const void* xraw, const void* segraw,
                                                     void* outraw,
                                                     const char* __restrict__ ws) {
  __shared__ Smem sm;
  const int tid = threadIdx.x, wi = blockIdx.x;
  const int bb = wi / WPB, hw0 = (wi - bb * WPB) * P;
  prologue<true>(xraw, segraw, sm, bb, hw0, tid);
  const bool isf32 = (sm.s_f32 > 16);
  if (isf32) stage<float>(xraw, sm.Xs, bb, hw0, tid);
  else       stage<__hip_bfloat16>(xraw, sm.Xs, bb, hw0, tid);
  __syncthreads();

  const unsigned short* WB  = (const unsigned short*)(ws + WB_OFF);
  const unsigned short* WB4 = (const unsigned short*)(ws + WB4_OFF);
  const float* BS  = (const float*)(ws + BIAS_OFF);
  const float* BS4 = (const float*)(ws + BIAS4_OFF);

  layerP<false, false>(sm.Xs, sm.Ys, WB,              BS,        sm, tid); __syncthreads();
  layerP<true,  false>(sm.Ys, sm.Xs, WB + 4 * 16384,  BS + 512,  sm, tid); __syncthreads();
  layerP<false, true >(sm.Xs, sm.Ys, WB + 8 * 16384,  BS + 1024, sm, tid); __syncthreads();
  layerP<true,  false>(sm.Ys, sm.Xs, WB + 12 * 16384, BS + 1536, sm, tid); __syncthreads();
  float* Obuf = (float*)sm.Ys;                 // Ys dead; [P][61] f32 = 23424 B
  layer5P(sm.Xs, Obuf, WB4, BS4, sm, tid);     __syncthreads();

  if (isf32) output<float>(outraw, Obuf, bb, hw0, tid);
  else       output<__hip_bfloat16>(outraw, Obuf, bb, hw0, tid);
}

// ---------------- fallback (no workspace): direct global weights ------------
template<typename T, bool LRELU, bool RES>
__device__ __forceinline__ void layerF(const unsigned short (*src)[kC],
                                       unsigned short (*dst)[kC],
                                       const T* __restrict__ W,
                                       const T* __restrict__ bia,
                                       const Smem& sm, int tid) {
  const int wave = tid >> 6, lane = tid & 63, quad = lane >> 4, col = lane & 15;
  const int rb = wave & 3, ch2 = wave >> 2;
  const int gs = sm.gpre[ch2 * 2], ge = sm.gpre[ch2 * 2 + 2];
  int curk = -1;
  bf16x8 a[2][4];
  float bs[2][4];
  for (int g = gs; g < ge; ++g) {
    const int k = sm.kg[g];
    if (k != curk) {
      curk = k;
      const T* Wk = W + (size_t)k * kC * kC;
      const T* bk = bia + (size_t)k * kC;
#pragma unroll
      for (int oi = 0; oi < 2; ++oi) {
        const int ra = rb * 32 + oi * 16 + col;
#pragma unroll
        for (int ks = 0; ks < 4; ++ks)
          a[oi][ks] = load_wfrag(Wk + (size_t)ra * kC + ks * 32 + quad * 8);
#pragma unroll
        for (int r = 0; r < 4; ++r)
          bs[oi][r] = load1(bk + rb * 32 + oi * 16 + quad * 4 + r);
      }
    }
    const int ov  = sm.ord[g * 16 + col];
    const int row = ov & 255;
    bf16x8 bfr[4];
#pragma unroll
    for (int ks = 0; ks < 4; ++ks)
      bfr[ks] = *reinterpret_cast<const bf16x8*>(&src[row][xgrp(row, ks * 4 + quad) * 8]);
#pragma unroll
    for (int oi = 0; oi < 2; ++oi) {
      f32x4 acc = {0.f, 0.f, 0.f, 0.f};
#pragma unroll
      for (int ks = 0; ks < 4; ++ks)
        acc = __builtin_amdgcn_mfma_f32_16x16x32_bf16(a[oi][ks], bfr[ks], acc, 0, 0, 0);
      if (ov < 256) {
        const int nb = rb * 32 + oi * 16 + quad * 4;
        unsigned short* dp = &dst[row][xgrp(row, nb >> 3) * 8 + (nb & 7)];
        float v[4];
#pragma unroll
        for (int r = 0; r < 4; ++r) {
          float t = acc[r] + bs[oi][r];
          if constexpr (LRELU) t = (t >= 0.f) ? t : kSlope * t;
          v[r] = t;
        }
        if constexpr (RES) {
          const short4 rv = *reinterpret_cast<const short4*>(dp);
          v[0] += bf2f((unsigned short)rv.x);
          v[1] += bf2f((unsigned short)rv.y);
          v[2] += bf2f((unsigned short)rv.z);
          v[3] += bf2f((unsigned short)rv.w);
        }
        short4 pk;
        pk.x = (short)f2bf(v[0]); pk.y = (short)f2bf(v[1]);
        pk.z = (short)f2bf(v[2]); pk.w = (short)f2bf(v[3]);
        *reinterpret_cast<short4*>(dp) = pk;
      }
    }
  }
}

template<typename T>
__device__ __forceinline__ void layer5F(const unsigned short (*src)[kC],
                                        float* __restrict__ Obuf,
                                        const T* __restrict__ W4,
                                        const T* __restrict__ b4,
                                        const Smem& sm, int tid) {
  const int wave = tid >> 6, lane = tid & 63, quad = lane >> 4, col = lane & 15;
  const int rb = wave & 3, ch2 = wave >> 2;
  const int gs = sm.gpre[ch2 * 2], ge = sm.gpre[ch2 * 2 + 2];
  int curk = -1;
  bf16x8 a[4];
  float bs[4];
  for (int g = gs; g < ge; ++g) {
    const int k = sm.kg[g];
    if (k != curk) {
      curk = k;
      const T* Wk = W4 + (size_t)k * kO * kC;
      const T* bk = b4 + (size_t)k * kO;
      const int ra = min(rb * 16 + col, kO - 1);
#pragma unroll
      for (int ks = 0; ks < 4; ++ks)
        a[ks] = load_wfrag(Wk + (size_t)ra * kC + ks * 32 + quad * 8);
#pragma unroll
      for (int r = 0; r < 4; ++r) {
        const int n = rb * 16 + quad * 4 + r;
        bs[r] = (n < kO) ? load1(bk + n) : 0.f;
      }
    }
    const int ov  = sm.ord[g * 16 + col];
    const int row = ov & 255;
    bf16x8 bfr[4];
#pragma unroll
    for (int ks = 0; ks < 4; ++ks)
      bfr[ks] = *reinterpret_cast<const bf16x8*>(&src[row][xgrp(row, ks * 4 + quad) * 8]);
    f32x4 acc = {0.f, 0.f, 0.f, 0.f};
#pragma unroll
    for (int ks = 0; ks < 4; ++ks)
      acc = __builtin_amdgcn_mfma_f32_16x16x32_bf16(a[ks], bfr[ks], acc, 0, 0, 0);
    if (ov < 256) {
#pragma unroll
      for (int r = 0; r < 4; ++r) {
        const int n = rb * 16 + quad * 4 + r;
        if (n < kO) Obuf[row * 61 + n] = acc[r] + bs[r];
      }
    }
  }
}

template<typename T>
__device__ __forceinline__ void run_fall(
    const void* xraw, void* outraw,
    const void* W1, const void* b1, const void* Wr1, const void* br1,
    const void* Wr2, const void* br2, const void* W3, const void* b3,
    const void* W4, const void* b4,
    Smem& sm, int bb, int hw0, int tid) {
  stage<T>(xraw, sm.Xs, bb, hw0, tid);
  __syncthreads();
  layerF<T, false, false>(sm.Xs, sm.Ys, (const T*)W1,  (const T*)b1,  sm, tid); __syncthreads();
  layerF<T, true,  false>(sm.Ys, sm.Xs, (const T*)Wr1, (const T*)br1, sm, tid); __syncthreads();
  layerF<T, false, true >(sm.Xs, sm.Ys, (const T*)Wr2, (const T*)br2, sm, tid); __syncthreads();
  layerF<T, true,  false>(sm.Ys, sm.Xs, (const T*)W3,  (const T*)b3,  sm, tid); __syncthreads();
  float* Obuf = (float*)sm.Ys;
  layer5F<T>(sm.Xs, Obuf, (const T*)W4, (const T*)b4, sm, tid);
  __syncthreads();
  output<T>(outraw, Obuf, bb, hw0, tid);
}

__global__ __launch_bounds__(512) void fused_fallback(
    const void* xraw, const void* segraw,
    const void* W1, const void* b1, const void* Wr1, const void* br1,
    const void* Wr2, const void* br2, const void* W3, const void* b3,
    const void* W4, const void* b4, void* outraw) {
  __shared__ Smem sm;
  const int tid = threadIdx.x, wi = blockIdx.x;
  const int bb = wi / WPB, hw0 = (wi - bb * WPB) * P;
  prologue<true>(xraw, segraw, sm, bb, hw0, tid);
  if (sm.s_f32 > 16)
    run_fall<float>(xraw, outraw, W1, b1, Wr1, br1, Wr2, br2, W3, b3, W4, b4,
                    sm, bb, hw0, tid);
  else
    run_fall<__hip_bfloat16>(xraw, outraw, W1, b1, Wr1, br1, Wr2, br2, W3, b3, W4, b4,
                             sm, bb, hw0, tid);
}

extern "C" void kernel_launch(void* const* d_in, const int* in_sizes, int n_in,
                              void* d_out, int out_size, void* d_ws, size_t ws_size,
                              hipStream_t stream) {
  (void)in_sizes; (void)n_in; (void)out_size;
  const int prep = (d_ws != nullptr && ws_size >= WS_NEED) ? 1 : 0;
  if (prep) {
    prep_kernel<<<153, 256, 0, stream>>>(
        d_in[2], d_in[4], d_in[6], d_in[8], d_in[10],
        d_in[3], d_in[5], d_in[7], d_in[9], d_in[11], (char*)d_ws);
    fused_main<<<NWIN, 512, 0, stream>>>(d_in[0], d_in[1], d_out, (const char*)d_ws);
  } else {
    fused_fallback<<<NWIN, 512, 0, stream>>>(
        d_in[0], d_in[1], d_in[2], d_in[3], d_in[4], d_in[5], d_in[6], d_in[7],
        d_in[8], d_in[9], d_in[10], d_in[11], d_out);
  }
}